// Round 10
// baseline (2450.711 us; speedup 1.0000x reference)
//
#include <hip/hip_runtime.h>
#include <hip/hip_bf16.h>
#include <math.h>

#define GN 19            // graph nodes
#define BB 256
#define TT 256
#define NG (BB * TT)     // 65536 graphs
#define NEB 240          // encoder blocks
#define NS (NEB * 8)     // 1920 encoder wave-streams

typedef short short8 __attribute__((ext_vector_type(8)));
typedef float f4 __attribute__((ext_vector_type(4)));
typedef unsigned short u16;

union Frag { int i[4]; short8 s; };

#define LWAIT() __asm__ volatile("s_waitcnt lgkmcnt(0)" ::: "memory")
#define WGBAR() __asm__ volatile("s_waitcnt lgkmcnt(0)\ns_barrier" ::: "memory")
#define PIN8(x) __asm__ volatile("" : "+v"(x))
#define PINF(x) __asm__ volatile("" : "+v"(x))

#define MFMA(a,b,c) __builtin_amdgcn_mfma_f32_16x16x32_bf16(a,b,c,0,0,0)

__device__ __forceinline__ int pkbf(float a, float b) {
    __hip_bfloat162 h2 = __float22bfloat162_rn(make_float2(a, b));
    union { __hip_bfloat162 h; int i; } u; u.h = h2; return u.i;
}
__device__ __forceinline__ u16 bf16of(float v) {
    return (u16)(unsigned)pkbf(v, v);
}

__device__ __forceinline__ float fexp2(float x) { return __builtin_amdgcn_exp2f(x); }
__device__ __forceinline__ float frcp(float x)  { return __builtin_amdgcn_rcpf(x); }
__device__ __forceinline__ float sigm(float x)  { return frcp(1.f + fexp2(-1.4426950408889634f * x)); }
__device__ __forceinline__ float tanha(float x) { float e = fexp2(2.8853900817779268f * x); return 1.f - 2.f * frcp(e + 1.f); }

// consumer gate: all lanes poll (same cacheline), agent-scope acquire
__device__ __forceinline__ void wait_cnt(const int* __restrict__ cnt, int t) {
    while (__hip_atomic_load((int*)&cnt[t], __ATOMIC_ACQUIRE,
                             __HIP_MEMORY_SCOPE_AGENT) < BB)
        __builtin_amdgcn_s_sleep(8);
}

__device__ __forceinline__ void read_h1(const u16* __restrict__ hs,
                                        int off, Frag* __restrict__ BH)
{
    #pragma unroll
    for (int kt = 0; kt < 2; ++kt) {
        int4 vh = *(const int4*)&hs[off + kt * 32];
        BH[kt].i[0] = vh.x; BH[kt].i[1] = vh.y;
        BH[kt].i[2] = vh.z; BH[kt].i[3] = vh.w;
    }
}

// ---------------------------------------------------------------------------
// FUSED producer-consumer kernel.  256 blocks x 512 threads, waves_per_eu
// (2,2) -> exactly 1 block/CU, all blocks co-resident (producer never waits
// on consumer -> no deadlock; worst case degenerates to serial).
//  - blocks 0..15: R5 LSTM (measured 260us), plus a per-step gate
//    cnt[t] >= 256 before prefetching X(t).
//  - blocks 16..255: R8 encoder (8 wave-streams/block = 1920 streams),
//    t-major graph order (o = k*1920+stream; t=o>>8, b=o&255) so timestep
//    completion is ~linear in wall time (~1.02 steps/us, just ahead of the
//    LSTM's ~1.0 us/step).  Per graph: emb stores -> threadfence ->
//    atomicAdd(cnt[t],1) release.
//  - MFMA1/MFMA3 LDS writes fused to ds_write_b64 (same bits, -48 ops/graph)
//    to keep the producer ahead of the consumer.
// ---------------------------------------------------------------------------
__global__ __launch_bounds__(512) __attribute__((amdgpu_waves_per_eu(2, 2)))
void fused(
    const float* __restrict__ conn,   // (G,19,19)
    const int*   __restrict__ mask,   // (B,T)
    const float* __restrict__ w1_w, const float* __restrict__ w1_b,
    const float* __restrict__ w2_w, const float* __restrict__ w2_b,
    const float* __restrict__ Wih0, const float* __restrict__ Whh0,
    const float* __restrict__ bih0, const float* __restrict__ bhh0,
    const float* __restrict__ Wih1, const float* __restrict__ Whh1,
    const float* __restrict__ bih1, const float* __restrict__ bhh1,
    const float* __restrict__ fc1_w, const float* __restrict__ fc1_b,
    const float* __restrict__ fc2_w, const float* __restrict__ fc2_b,
    u16* __restrict__ emb,            // (G,64) bf16 (workspace)
    int* __restrict__ cnt,            // (T) produced-graph counters (ws)
    float* __restrict__ out)          // (B,2)
{
    // shared: encoder needs 54272B, lstm 15680B -> one buffer, two views
    __shared__ __attribute__((aligned(16))) unsigned char SMEM[54272];

    const int tid  = threadIdx.x;     // 0..511
    const int w    = tid >> 6;        // wave 0..7
    const int lane = tid & 63;
    const int l15  = lane & 15;
    const int quad = lane >> 4;

    if (blockIdx.x >= 16) {
        // ================= ENCODER (producer) =================
        float* SA   = (float*)SMEM;                  // [8][1280]
        u16*   wb   = (u16*)(SMEM + 40960);          // [12][64][8]
        float* disA = (float*)(SMEM + 53248);        // [8][32]

        // stage weight B-frags once per block (wave 0)
        if (w == 0) {
            #pragma unroll
            for (int nt = 0; nt < 4; ++nt) {
                int n = nt * 16 + l15;
                Frag f;
                #pragma unroll
                for (int p = 0; p < 4; ++p) {
                    int k0 = quad * 8 + 2 * p, k1 = k0 + 1;
                    float a = (k0 < GN) ? w1_w[n * GN + k0] : 0.f;
                    float b = (k1 < GN) ? w1_w[n * GN + k1] : 0.f;
                    f.i[p] = pkbf(a, b);
                }
                *(int4*)&wb[(nt * 64 + lane) * 8] = *(int4*)&f;
            }
            #pragma unroll
            for (int kt = 0; kt < 2; ++kt)
                #pragma unroll
                for (int nt = 0; nt < 4; ++nt) {
                    int n = nt * 16 + l15;
                    Frag f;
                    #pragma unroll
                    for (int p = 0; p < 4; ++p) {
                        int k = kt * 32 + quad * 8 + 2 * p;
                        f.i[p] = pkbf(w2_w[n * 64 + k], w2_w[n * 64 + k + 1]);
                    }
                    *(int4*)&wb[((4 + kt * 4 + nt) * 64 + lane) * 8] = *(int4*)&f;
                }
        }
        float b1v[4], b2v[4];
        #pragma unroll
        for (int nt = 0; nt < 4; ++nt) {
            b1v[nt] = w1_b[nt * 16 + l15];
            b2v[nt] = w2_b[nt * 16 + l15];
        }
        __syncthreads();   // wb ready; waves independent afterwards

        float* __restrict__ S   = SA + w * 1280;     // A region [32][36] f32
        u16*  __restrict__ SH   = (u16*)S;           // H^T [64][40] u16
        u16*  __restrict__ SX   = (u16*)S;           // X1 [32][40] u16
        float* __restrict__ dis = disA + w * 32;

        int rr[6], cc[6];
        #pragma unroll
        for (int i = 0; i < 6; ++i) {
            int e = lane + 64 * i;
            rr[i] = e / GN;
            cc[i] = e - rr[i] * GN;
        }

        const int es = (blockIdx.x - 16) * 8 + w;    // stream id 0..1919

        float pf[6];
        {
            int o0 = es;
            int g0 = ((o0 & 255) << 8) | (o0 >> 8);
            const float* Ag = conn + (size_t)g0 * (GN * GN);
            #pragma unroll
            for (int i = 0; i < 6; ++i) {
                int e = lane + 64 * i;
                if (e < GN * GN) pf[i] = Ag[e];
            }
        }

        #pragma unroll 1
        for (int o = es; o < NG; o += NS) {
            const int tg = o >> 8;
            const int g  = ((o & 255) << 8) | tg;

            #pragma unroll
            for (int i = 0; i < 4; ++i) {
                int s = lane + 64 * i;
                int row = s >> 3, c4 = s & 7;
                f4 z = {0.f, 0.f, 0.f, 0.f};
                *(f4*)&S[row * 36 + c4 * 4] = z;
            }
            LWAIT();
            #pragma unroll
            for (int i = 0; i < 6; ++i) {
                if (lane + 64 * i < GN * GN) S[rr[i] * 36 + cc[i]] = pf[i];
            }
            {
                int on = o + NS;
                int gn = (on < NG) ? (((on & 255) << 8) | (on >> 8)) : g;
                const float* Ag = conn + (size_t)gn * (GN * GN);
                #pragma unroll
                for (int i = 0; i < 6; ++i) {
                    int e = lane + 64 * i;
                    if (e < GN * GN) pf[i] = Ag[e];
                }
            }
            LWAIT();

            if (lane < 32) {
                float dv = 0.f;
                if (lane < GN) {
                    float d = 1.0f;
                    #pragma unroll
                    for (int c4 = 0; c4 < 8; ++c4) {
                        f4 v = *(f4*)&S[lane * 36 + c4 * 4];
                        d += v.x + v.y + v.z + v.w;
                    }
                    dv = rsqrtf(d);
                }
                dis[lane] = dv;
            }
            LWAIT();

            float dk[8];
            {
                f4 v0 = *(f4*)&dis[quad * 8];
                f4 v1 = *(f4*)&dis[quad * 8 + 4];
                dk[0]=v0.x; dk[1]=v0.y; dk[2]=v0.z; dk[3]=v0.w;
                dk[4]=v1.x; dk[5]=v1.y; dk[6]=v1.z; dk[7]=v1.w;
            }
            Frag aF[2], anF[2];
            #pragma unroll
            for (int mt = 0; mt < 2; ++mt) {
                int m = l15 + 16 * mt;
                float dm = dis[m];
                f4 v0 = *(f4*)&S[m * 36 + quad * 8];
                f4 v1 = *(f4*)&S[m * 36 + quad * 8 + 4];
                float av[8] = {v0.x, v0.y, v0.z, v0.w, v1.x, v1.y, v1.z, v1.w};
                float an[8];
                #pragma unroll
                for (int j = 0; j < 8; ++j) {
                    int k = quad * 8 + j;
                    an[j] = (av[j] + (m == k ? 1.f : 0.f)) * dm * dk[j];
                }
                #pragma unroll
                for (int p = 0; p < 4; ++p) {
                    aF[mt].i[p]  = pkbf(av[2*p], av[2*p+1]);
                    anF[mt].i[p] = pkbf(an[2*p], an[2*p+1]);
                }
            }
            LWAIT();

            // MFMA1: H1 = A @ W1^T + b1 -> SH bf16 (b64 writes, k>=19 zeroed)
            #pragma unroll
            for (int nt = 0; nt < 4; ++nt) {
                Frag wf; *(int4*)&wf = *(int4*)&wb[(nt * 64 + lane) * 8];
                int nn = nt * 16 + l15;
                #pragma unroll
                for (int mt = 0; mt < 2; ++mt) {
                    float bb = b1v[nt];
                    f4 c = {bb, bb, bb, bb};
                    c = MFMA(aF[mt].s, wf.s, c);
                    float v0 = c[0], v1 = c[1], v2 = c[2], v3 = c[3];
                    if (mt == 1) {
                        if (quad != 0) { v0 = v1 = v2 = v3 = 0.f; }
                        else v3 = 0.f;
                    }
                    int2 pk;
                    pk.x = pkbf(v0, v1);
                    pk.y = pkbf(v2, v3);
                    *(int2*)&SH[nn * 40 + mt * 16 + quad * 4] = pk;
                }
            }
            LWAIT();

            Frag hF[4];
            #pragma unroll
            for (int nt = 0; nt < 4; ++nt)
                *(int4*)&hF[nt] = *(const int4*)&SH[(nt * 16 + l15) * 40 + quad * 8];
            LWAIT();

            // MFMA2: X1 = relu(An @ H1) -> SX bf16 row-major
            #pragma unroll
            for (int nt = 0; nt < 4; ++nt) {
                int nn = nt * 16 + l15;
                #pragma unroll
                for (int mt = 0; mt < 2; ++mt) {
                    f4 c = {0.f, 0.f, 0.f, 0.f};
                    c = MFMA(anF[mt].s, hF[nt].s, c);
                    #pragma unroll
                    for (int r = 0; r < 4; ++r) {
                        int m = mt * 16 + quad * 4 + r;
                        SX[m * 40 + nn] = bf16of(fmaxf(c[r], 0.f));
                    }
                }
            }
            LWAIT();

            Frag xF[2][2];
            #pragma unroll
            for (int mt = 0; mt < 2; ++mt) {
                int m = l15 + 16 * mt;
                #pragma unroll
                for (int kt = 0; kt < 2; ++kt)
                    *(int4*)&xF[mt][kt] = *(const int4*)&SX[m * 40 + kt * 32 + quad * 8];
            }
            LWAIT();

            // MFMA3: H2 = X1 @ W2^T + b2 -> SH bf16 (b64 writes, masked)
            #pragma unroll
            for (int nt = 0; nt < 4; ++nt) {
                Frag w20; *(int4*)&w20 = *(int4*)&wb[((4 + nt) * 64 + lane) * 8];
                Frag w21; *(int4*)&w21 = *(int4*)&wb[((8 + nt) * 64 + lane) * 8];
                int nn = nt * 16 + l15;
                #pragma unroll
                for (int mt = 0; mt < 2; ++mt) {
                    float bb = b2v[nt];
                    f4 c = {bb, bb, bb, bb};
                    c = MFMA(xF[mt][0].s, w20.s, c);
                    c = MFMA(xF[mt][1].s, w21.s, c);
                    float v0 = c[0], v1 = c[1], v2 = c[2], v3 = c[3];
                    if (mt == 1) {
                        if (quad != 0) { v0 = v1 = v2 = v3 = 0.f; }
                        else v3 = 0.f;
                    }
                    int2 pk;
                    pk.x = pkbf(v0, v1);
                    pk.y = pkbf(v2, v3);
                    *(int2*)&SH[nn * 40 + mt * 16 + quad * 4] = pk;
                }
            }
            LWAIT();

            // MFMA4: X2 = relu(An @ H2); column sums -> emb mean
            float cs[4];
            #pragma unroll
            for (int nt = 0; nt < 4; ++nt) {
                Frag hG; *(int4*)&hG = *(const int4*)&SH[(nt * 16 + l15) * 40 + quad * 8];
                float acc = 0.f;
                #pragma unroll
                for (int mt = 0; mt < 2; ++mt) {
                    f4 c = {0.f, 0.f, 0.f, 0.f};
                    c = MFMA(anF[mt].s, hG.s, c);
                    if (mt == 0) {
                        acc += fmaxf(c[0], 0.f) + fmaxf(c[1], 0.f)
                             + fmaxf(c[2], 0.f) + fmaxf(c[3], 0.f);
                    } else if (quad == 0) {
                        acc += fmaxf(c[0], 0.f) + fmaxf(c[1], 0.f) + fmaxf(c[2], 0.f);
                    }
                }
                cs[nt] = acc;
            }
            #pragma unroll
            for (int nt = 0; nt < 4; ++nt) {
                cs[nt] += __shfl_xor(cs[nt], 16);
                cs[nt] += __shfl_xor(cs[nt], 32);
            }
            float tot = cs[0];
            tot = (quad == 1) ? cs[1] : tot;
            tot = (quad == 2) ? cs[2] : tot;
            tot = (quad == 3) ? cs[3] : tot;
            float mf = (float)mask[g];
            float v = tot * (1.f / 19.f) * mf;
            emb[(size_t)g * 64 + lane] = bf16of(v);

            // publish: emb visible (device scope) before counter bump
            __threadfence();
            if (lane == 0)
                __hip_atomic_fetch_add(&cnt[tg], 1, __ATOMIC_RELEASE,
                                       __HIP_MEMORY_SCOPE_AGENT);
            LWAIT();   // SH reads done before next iteration's zeros
        }
        return;
    }

    // ================= LSTM (consumer) — R5 body + gates =================
    u16*   h0s   = (u16*)SMEM;                       // [2][1152]
    u16*   h1s   = (u16*)(SMEM + 4608);              // [2][1152]
    float* hlast = (float*)(SMEM + 9216);            // [16][68]
    float* red   = (float*)(SMEM + 13568);           // [512]
    int*   li_s  = (int*)(SMEM + 15616);             // [16]

    const int grp  = w >> 2;          // 0: layer 0 (waves 0-3), 1: layer 1
    const int wl   = w & 3;
    const int bb0  = blockIdx.x * 16;

    for (int i = tid; i < 1152; i += 512) h1s[i] = 0;   // h1 dbuf[0]

    {
        int b16 = tid >> 5, j = tid & 31;
        int s = 0;
        #pragma unroll
        for (int c8 = 0; c8 < 8; ++c8)
            s += mask[(bb0 + b16) * TT + j + 32 * c8];
        red[tid] = (float)s;
    }
    __syncthreads();
    if (tid < 16) {
        float s = 0.f;
        #pragma unroll
        for (int j = 0; j < 32; ++j) s += red[tid * 32 + j];
        int li = (int)s - 1;
        li_s[tid] = li < 0 ? 0 : (li > TT - 1 ? TT - 1 : li);
    }
    __syncthreads();
    const int li = li_s[l15];

    const float* __restrict__ Wx = grp ? Wih1 : Wih0;
    const float* __restrict__ Wh = grp ? Whh1 : Whh0;
    const float* __restrict__ bi = grp ? bih1 : bih0;
    const float* __restrict__ bh = grp ? bhh1 : bhh0;

    Frag Ax[4][2], Ah[4][2];
    f4 biasv[4];
    #pragma unroll
    for (int mt = 0; mt < 4; ++mt) {
        int mg = 4 * wl + mt;
        int orig = (l15 & 3) * 64 + (mg * 4 + (l15 >> 2));
        #pragma unroll
        for (int kt = 0; kt < 2; ++kt)
            #pragma unroll
            for (int p = 0; p < 4; ++p) {
                int k = kt * 32 + quad * 8 + 2 * p;
                Ax[mt][kt].i[p] = pkbf(Wx[orig * 64 + k], Wx[orig * 64 + k + 1]);
                Ah[mt][kt].i[p] = pkbf(Wh[orig * 64 + k], Wh[orig * 64 + k + 1]);
            }
        int uu = mg * 4 + quad;
        #pragma unroll
        for (int r = 0; r < 4; ++r)
            biasv[mt][r] = bi[r * 64 + uu] + bh[r * 64 + uu];
    }
    #pragma unroll
    for (int mt = 0; mt < 4; ++mt) {
        PIN8(Ax[mt][0].s); PIN8(Ax[mt][1].s);
        PIN8(Ah[mt][0].s); PIN8(Ah[mt][1].s);
        PINF(biasv[mt]);
    }

    const int ubase = 16 * wl + quad;
    const int hoff = l15 * 72 + quad * 8;

    Frag BH0[2], BH1[2], BXn[2];
    #pragma unroll
    for (int kt = 0; kt < 2; ++kt)
        #pragma unroll
        for (int p = 0; p < 4; ++p) {
            BXn[kt].i[p] = 0; BH0[kt].i[p] = 0; BH1[kt].i[p] = 0;
        }
    float cst[4] = {0.f, 0.f, 0.f, 0.f};
    float hlv[4] = {0.f, 0.f, 0.f, 0.f};

    const u16* __restrict__ xb = emb + (size_t)(bb0 + l15) * TT * 64;
    if (grp == 0) {
        wait_cnt(cnt, 0);                       // gate X(0)
        BXn[0] = *(const Frag*)&xb[quad * 8];
        BXn[1] = *(const Frag*)&xb[32 + quad * 8];
    }

    #pragma unroll 1
    for (int it = 0; it <= TT; ++it) {
        const int cur = it & 1;
        f4 g[4];
        bool act = false;

        if (grp == 0) {
            if (it < TT) {
                act = true;
                Frag bx0 = BXn[0], bx1 = BXn[1];
                int tn = it + 1 < TT ? it + 1 : TT - 1;
                if (it + 1 < TT) wait_cnt(cnt, tn);     // gate X(it+1)
                BXn[0] = *(const Frag*)&xb[(size_t)tn * 64 + quad * 8];
                BXn[1] = *(const Frag*)&xb[(size_t)tn * 64 + 32 + quad * 8];

                #pragma unroll
                for (int mt = 0; mt < 4; ++mt) {
                    f4 ca = biasv[mt];
                    ca = MFMA(Ax[mt][0].s, bx0.s,    ca);
                    ca = MFMA(Ah[mt][0].s, BH0[0].s, ca);
                    f4 cb = {0.f, 0.f, 0.f, 0.f};
                    cb = MFMA(Ax[mt][1].s, bx1.s,    cb);
                    cb = MFMA(Ah[mt][1].s, BH0[1].s, cb);
                    g[mt] = ca + cb;
                }
            }
        } else {
            if (it >= 1) {
                act = true;
                #pragma unroll
                for (int mt = 0; mt < 4; ++mt) {
                    f4 ca = biasv[mt];
                    ca = MFMA(Ax[mt][0].s, BH0[0].s, ca);
                    ca = MFMA(Ah[mt][0].s, BH1[0].s, ca);
                    f4 cb = {0.f, 0.f, 0.f, 0.f};
                    cb = MFMA(Ax[mt][1].s, BH0[1].s, cb);
                    cb = MFMA(Ah[mt][1].s, BH1[1].s, cb);
                    g[mt] = ca + cb;
                }
            }
        }

        if (act) {
            u16* __restrict__ dst = (grp ? h1s : h0s) + cur * 1152;
            #pragma unroll
            for (int mt = 0; mt < 4; ++mt) {
                f4 gg = g[mt];
                float si = sigm(gg[0]), sf = sigm(gg[1]);
                float tg = tanha(gg[2]), so = sigm(gg[3]);
                float cc = fmaf(sf, cst[mt], si * tg);
                cst[mt] = cc;
                float h = so * tanha(cc);
                if (grp && it - 1 == li) hlv[mt] = h;
                dst[l15 * 72 + ubase + 4 * mt] = (u16)(unsigned)pkbf(h, h);
            }
        }

        WGBAR();

        if (it < TT) {
            read_h1(h0s + cur * 1152, hoff, BH0);
            if (grp) read_h1(h1s + cur * 1152, hoff, BH1);
        }
    }

    if (grp == 1) {
        #pragma unroll
        for (int mt = 0; mt < 4; ++mt)
            hlast[l15 * 68 + ubase + 4 * mt] = hlv[mt];
    }
    __syncthreads();
    {
        int b = tid >> 5, o = tid & 31;
        float acc = fc1_b[o];
        const float* fw = fc1_w + o * 64;
        #pragma unroll
        for (int j = 0; j < 64; ++j)
            acc = fmaf(hlast[b * 68 + j], fw[j], acc);
        red[b * 32 + o] = fmaxf(acc, 0.f);
    }
    __syncthreads();
    if (tid < 32) {
        int b = tid >> 1, o = tid & 1;
        float acc = fc2_b[o];
        #pragma unroll
        for (int j = 0; j < 32; ++j)
            acc = fmaf(fc2_w[o * 32 + j], red[b * 32 + j], acc);
        out[(bb0 + b) * 2 + o] = acc;
    }
}

// ---------------------------------------------------------------------------
extern "C" void kernel_launch(void* const* d_in, const int* in_sizes, int n_in,
                              void* d_out, int out_size, void* d_ws, size_t ws_size,
                              hipStream_t stream)
{
    const float* conn  = (const float*)d_in[0];
    const int*   mask  = (const int*)  d_in[1];
    const float* w1_w  = (const float*)d_in[2];
    const float* w1_b  = (const float*)d_in[3];
    const float* w2_w  = (const float*)d_in[4];
    const float* w2_b  = (const float*)d_in[5];
    const float* Wih0  = (const float*)d_in[6];
    const float* Whh0  = (const float*)d_in[7];
    const float* bih0  = (const float*)d_in[8];
    const float* bhh0  = (const float*)d_in[9];
    const float* Wih1  = (const float*)d_in[10];
    const float* Whh1  = (const float*)d_in[11];
    const float* bih1  = (const float*)d_in[12];
    const float* bhh1  = (const float*)d_in[13];
    const float* fc1_w = (const float*)d_in[14];
    const float* fc1_b = (const float*)d_in[15];
    const float* fc2_w = (const float*)d_in[16];
    const float* fc2_b = (const float*)d_in[17];

    float* out = (float*)d_out;
    u16*   emb = (u16*)d_ws;                              // 8.4 MB bf16
    int*   cnt = (int*)((char*)d_ws + (size_t)NG * 64 * sizeof(u16));

    hipMemsetAsync(cnt, 0, TT * sizeof(int), stream);

    fused<<<16 + NEB, 512, 0, stream>>>(
        conn, mask, w1_w, w1_b, w2_w, w2_b,
        Wih0, Whh0, bih0, bhh0, Wih1, Whh1, bih1, bhh1,
        fc1_w, fc1_b, fc2_w, fc2_b,
        emb, cnt, out);
}

// Round 12
// 501.002 us; speedup vs baseline: 4.8916x; 4.8916x over previous
//
#include <hip/hip_runtime.h>
#include <hip/hip_bf16.h>
#include <math.h>

#define GN 19            // graph nodes
#define BB 256
#define TT 256

typedef short short8 __attribute__((ext_vector_type(8)));
typedef float f4 __attribute__((ext_vector_type(4)));
typedef unsigned short u16;

union Frag { int i[4]; short8 s; };

// wave-local LDS ordering fence: wait LDS ops, NO vmcnt drain, no barrier.
#define LWAIT() __asm__ volatile("s_waitcnt lgkmcnt(0)" ::: "memory")
// workgroup barrier WITHOUT vmcnt(0) drain: global loads stay in flight.
#define WGBAR() __asm__ volatile("s_waitcnt lgkmcnt(0)\ns_barrier" ::: "memory")
// opaque-register pin
#define PIN8(x) __asm__ volatile("" : "+v"(x))
#define PINF(x) __asm__ volatile("" : "+v"(x))

#define MFMA(a,b,c) __builtin_amdgcn_mfma_f32_16x16x32_bf16(a,b,c,0,0,0)

// packed RNE float pair -> bf16 pair (v_cvt_pk_bf16_f32 on gfx950)
__device__ __forceinline__ int pkbf(float a, float b) {
    __hip_bfloat162 h2 = __float22bfloat162_rn(make_float2(a, b));
    union { __hip_bfloat162 h; int i; } u; u.h = h2; return u.i;
}
__device__ __forceinline__ u16 bf16of(float v) {
    return (u16)(unsigned)pkbf(v, v);
}

__device__ __forceinline__ float fexp2(float x) { return __builtin_amdgcn_exp2f(x); }
__device__ __forceinline__ float frcp(float x)  { return __builtin_amdgcn_rcpf(x); }
__device__ __forceinline__ float sigm(float x)  { return frcp(1.f + fexp2(-1.4426950408889634f * x)); }
__device__ __forceinline__ float tanha(float x) { float e = fexp2(2.8853900817779268f * x); return 1.f - 2.f * frcp(e + 1.f); }

// ---------------------------------------------------------------------------
// Kernel A v3 (resubmission of R10 — infra ate the run, no kernel verdict).
// R9 structure (2048 blocks x 4 wave-streams, 16 waves/CU) + three issue
// cuts motivated by R9's "issue-bound" reading:
//  1. MFMA1/MFMA3 outputs written as ds_write_b64 with the k>=19 mask folded
//     in (bits ran verbatim in R9's passing fused kernel).
//  2. Degree phase FUSED into the pack phase: row sums via __shfl_xor(16/32)
//     on the A values the pack already loads -> deletes 8 ds_read_b128 +
//     the 32-lane add phase per graph.
//  3. mask[g] hoisted to loop top (LWAIT memory clobbers were pinning this
//     dependent HBM load into the last phase, exposing its latency).
// ---------------------------------------------------------------------------
__global__ __launch_bounds__(256) __attribute__((amdgpu_waves_per_eu(2, 4)))
void encoder_mfma(
    const float* __restrict__ conn,   // (G,19,19)
    const int*   __restrict__ mask,   // (G)
    const float* __restrict__ w1_w,   // (64,19)
    const float* __restrict__ w1_b,   // (64)
    const float* __restrict__ w2_w,   // (64,64)
    const float* __restrict__ w2_b,   // (64)
    u16* __restrict__ emb,            // (G,64) bf16
    int num_graphs)
{
    __shared__ __attribute__((aligned(16))) float SA[4][1280];   // 5120B/wave
    __shared__ __attribute__((aligned(16))) u16  wb[12][64][8];  // w1F(4)+w2F(8)
    __shared__ __attribute__((aligned(16))) float dis4[4][32];

    const int tid = threadIdx.x;
    const int tw  = tid >> 6;         // wave 0..3 (graph stream)
    const int t   = tid & 63;         // lane
    const int l15 = t & 15;
    const int quad = t >> 4;

    // ---- stage weight B-frags once per block (wave 0) ----
    if (tw == 0) {
        #pragma unroll
        for (int nt = 0; nt < 4; ++nt) {
            int n = nt * 16 + l15;
            Frag f;
            #pragma unroll
            for (int p = 0; p < 4; ++p) {
                int k0 = quad * 8 + 2 * p, k1 = k0 + 1;
                float a = (k0 < GN) ? w1_w[n * GN + k0] : 0.f;
                float b = (k1 < GN) ? w1_w[n * GN + k1] : 0.f;
                f.i[p] = pkbf(a, b);
            }
            *(int4*)&wb[nt][t][0] = *(int4*)&f;
        }
        #pragma unroll
        for (int kt = 0; kt < 2; ++kt)
            #pragma unroll
            for (int nt = 0; nt < 4; ++nt) {
                int n = nt * 16 + l15;
                Frag f;
                #pragma unroll
                for (int p = 0; p < 4; ++p) {
                    int k = kt * 32 + quad * 8 + 2 * p;
                    f.i[p] = pkbf(w2_w[n * 64 + k], w2_w[n * 64 + k + 1]);
                }
                *(int4*)&wb[4 + kt * 4 + nt][t][0] = *(int4*)&f;
            }
    }
    float b1v[4], b2v[4];
    #pragma unroll
    for (int nt = 0; nt < 4; ++nt) {
        b1v[nt] = w1_b[nt * 16 + l15];
        b2v[nt] = w2_b[nt * 16 + l15];
    }
    __syncthreads();   // wb ready; afterwards waves are fully independent

    float* __restrict__ S   = SA[tw];     // A region: [32][36] f32
    u16*  __restrict__ SH   = (u16*)S;    // H^T regions: [64][40] u16
    u16*  __restrict__ SX   = (u16*)S;    // X1 region: [32][40] u16
    float* __restrict__ dis = dis4[tw];

    int rr[6], cc[6];
    #pragma unroll
    for (int i = 0; i < 6; ++i) {
        int e = t + 64 * i;
        rr[i] = e / GN;
        cc[i] = e - rr[i] * GN;
    }

    float pf[6];
    {
        int g0 = blockIdx.x * 4 + tw;
        const float* Ag = conn + (size_t)g0 * (GN * GN);
        #pragma unroll
        for (int i = 0; i < 6; ++i) {
            int e = t + 64 * i;
            if (e < GN * GN) pf[i] = Ag[e];
        }
    }

    #pragma unroll 1
    for (int g = blockIdx.x * 4 + tw; g < num_graphs; g += gridDim.x * 4) {
        // mask prefetch: issue NOW so its latency hides under the pipeline
        const float mf = (float)mask[g];

        // zero A region [32 rows][cols 0..31], stride 36
        #pragma unroll
        for (int i = 0; i < 4; ++i) {
            int s = t + 64 * i;          // 256 f4 slots
            int row = s >> 3, c4 = s & 7;
            f4 z = {0.f, 0.f, 0.f, 0.f};
            *(f4*)&S[row * 36 + c4 * 4] = z;
        }
        LWAIT();
        #pragma unroll
        for (int i = 0; i < 6; ++i) {
            if (t + 64 * i < GN * GN) S[rr[i] * 36 + cc[i]] = pf[i];
        }
        {
            int gn = g + gridDim.x * 4;
            const float* Ag = conn + (size_t)(gn < num_graphs ? gn : g) * (GN * GN);
            #pragma unroll
            for (int i = 0; i < 6; ++i) {
                int e = t + 64 * i;
                if (e < GN * GN) pf[i] = Ag[e];
            }
        }
        LWAIT();

        // ---- pack phase A: read A rows, FUSED degree via shfl tree ----
        f4 v0s[2], v1s[2];
        float dmv[2];
        #pragma unroll
        for (int mt = 0; mt < 2; ++mt) {
            int m = l15 + 16 * mt;
            f4 v0 = *(f4*)&S[m * 36 + quad * 8];
            f4 v1 = *(f4*)&S[m * 36 + quad * 8 + 4];
            v0s[mt] = v0; v1s[mt] = v1;
            float s = ((v0.x + v0.y) + (v0.z + v0.w))
                    + ((v1.x + v1.y) + (v1.z + v1.w));
            s += __shfl_xor(s, 16);
            s += __shfl_xor(s, 32);
            float rs = rsqrtf(1.0f + s);
            dmv[mt] = (m < GN) ? rs : 0.f;
        }
        if (quad == 0) {
            dis[l15]      = dmv[0];
            dis[16 + l15] = dmv[1];
        }
        LWAIT();

        // ---- pack phase B: dk read + aF/anF pack ----
        float dk[8];
        {
            f4 w0 = *(f4*)&dis[quad * 8];
            f4 w1 = *(f4*)&dis[quad * 8 + 4];
            dk[0]=w0.x; dk[1]=w0.y; dk[2]=w0.z; dk[3]=w0.w;
            dk[4]=w1.x; dk[5]=w1.y; dk[6]=w1.z; dk[7]=w1.w;
        }
        Frag aF[2], anF[2];
        #pragma unroll
        for (int mt = 0; mt < 2; ++mt) {
            int m = l15 + 16 * mt;
            float dm = dmv[mt];
            f4 v0 = v0s[mt], v1 = v1s[mt];
            float av[8] = {v0.x, v0.y, v0.z, v0.w, v1.x, v1.y, v1.z, v1.w};
            float an[8];
            #pragma unroll
            for (int j = 0; j < 8; ++j) {
                int k = quad * 8 + j;
                an[j] = (av[j] + (m == k ? 1.f : 0.f)) * dm * dk[j];
            }
            #pragma unroll
            for (int p = 0; p < 4; ++p) {
                aF[mt].i[p]  = pkbf(av[2*p], av[2*p+1]);
                anF[mt].i[p] = pkbf(an[2*p], an[2*p+1]);
            }
        }
        LWAIT();   // all S reads retired before H1^T overwrites the bytes

        // MFMA1: H1 = A @ W1^T + b1 -> SH bf16 (b64 writes, k>=19 zeroed)
        #pragma unroll
        for (int nt = 0; nt < 4; ++nt) {
            Frag wf; *(int4*)&wf = *(int4*)&wb[nt][t][0];
            int nn = nt * 16 + l15;
            #pragma unroll
            for (int mt = 0; mt < 2; ++mt) {
                float bb = b1v[nt];
                f4 c = {bb, bb, bb, bb};
                c = MFMA(aF[mt].s, wf.s, c);
                float w0 = c[0], w1 = c[1], w2 = c[2], w3 = c[3];
                if (mt == 1) {
                    if (quad != 0) { w0 = w1 = w2 = w3 = 0.f; }
                    else w3 = 0.f;
                }
                int2 pk;
                pk.x = pkbf(w0, w1);
                pk.y = pkbf(w2, w3);
                *(int2*)&SH[nn * 40 + mt * 16 + quad * 4] = pk;
            }
        }
        LWAIT();

        // hF: pure b128 reads
        Frag hF[4];
        #pragma unroll
        for (int nt = 0; nt < 4; ++nt)
            *(int4*)&hF[nt] = *(const int4*)&SH[(nt * 16 + l15) * 40 + quad * 8];
        LWAIT();   // H1^T reads done before X1 overwrites

        // MFMA2: X1 = relu(An @ H1) -> SX bf16 row-major (rows>=19 are 0)
        #pragma unroll
        for (int nt = 0; nt < 4; ++nt) {
            int nn = nt * 16 + l15;
            #pragma unroll
            for (int mt = 0; mt < 2; ++mt) {
                f4 c = {0.f, 0.f, 0.f, 0.f};
                c = MFMA(anF[mt].s, hF[nt].s, c);
                #pragma unroll
                for (int r = 0; r < 4; ++r) {
                    int m = mt * 16 + quad * 4 + r;
                    SX[m * 40 + nn] = bf16of(fmaxf(c[r], 0.f));
                }
            }
        }
        LWAIT();

        // xF: pure b128 reads
        Frag xF[2][2];
        #pragma unroll
        for (int mt = 0; mt < 2; ++mt) {
            int m = l15 + 16 * mt;
            #pragma unroll
            for (int kt = 0; kt < 2; ++kt)
                *(int4*)&xF[mt][kt] = *(const int4*)&SX[m * 40 + kt * 32 + quad * 8];
        }
        LWAIT();   // X1 reads done before H2^T overwrites

        // MFMA3: H2 = X1 @ W2^T + b2 -> SH bf16 (b64 writes, masked)
        #pragma unroll
        for (int nt = 0; nt < 4; ++nt) {
            Frag w20; *(int4*)&w20 = *(int4*)&wb[4 + nt][t][0];
            Frag w21; *(int4*)&w21 = *(int4*)&wb[8 + nt][t][0];
            int nn = nt * 16 + l15;
            #pragma unroll
            for (int mt = 0; mt < 2; ++mt) {
                float bb = b2v[nt];
                f4 c = {bb, bb, bb, bb};
                c = MFMA(xF[mt][0].s, w20.s, c);
                c = MFMA(xF[mt][1].s, w21.s, c);
                float w0 = c[0], w1 = c[1], w2 = c[2], w3 = c[3];
                if (mt == 1) {
                    if (quad != 0) { w0 = w1 = w2 = w3 = 0.f; }
                    else w3 = 0.f;
                }
                int2 pk;
                pk.x = pkbf(w0, w1);
                pk.y = pkbf(w2, w3);
                *(int2*)&SH[nn * 40 + mt * 16 + quad * 4] = pk;
            }
        }
        LWAIT();

        // MFMA4: X2 = relu(An @ H2); column sums -> emb mean
        float cs[4];
        #pragma unroll
        for (int nt = 0; nt < 4; ++nt) {
            Frag hG; *(int4*)&hG = *(const int4*)&SH[(nt * 16 + l15) * 40 + quad * 8];
            float acc = 0.f;
            #pragma unroll
            for (int mt = 0; mt < 2; ++mt) {
                f4 c = {0.f, 0.f, 0.f, 0.f};
                c = MFMA(anF[mt].s, hG.s, c);
                if (mt == 0) {
                    acc += fmaxf(c[0], 0.f) + fmaxf(c[1], 0.f)
                         + fmaxf(c[2], 0.f) + fmaxf(c[3], 0.f);
                } else if (quad == 0) {
                    acc += fmaxf(c[0], 0.f) + fmaxf(c[1], 0.f) + fmaxf(c[2], 0.f);
                }
            }
            cs[nt] = acc;
        }
        #pragma unroll
        for (int nt = 0; nt < 4; ++nt) {
            cs[nt] += __shfl_xor(cs[nt], 16);
            cs[nt] += __shfl_xor(cs[nt], 32);
        }
        float tot = cs[0];
        tot = (quad == 1) ? cs[1] : tot;
        tot = (quad == 2) ? cs[2] : tot;
        tot = (quad == 3) ? cs[3] : tot;
        float v = tot * (1.f / 19.f) * mf;
        emb[(size_t)g * 64 + t] = bf16of(v);
        LWAIT();   // SH reads done before next iteration's zero overwrites
    }
}

// read single-bf16 h B-fragments straight from LDS (zero VALU)
__device__ __forceinline__ void read_h1(const u16* __restrict__ hs,
                                        int off, Frag* __restrict__ BH)
{
    #pragma unroll
    for (int kt = 0; kt < 2; ++kt) {
        int4 vh = *(const int4*)&hs[off + kt * 32];
        BH[kt].i[0] = vh.x; BH[kt].i[1] = vh.y;
        BH[kt].i[2] = vh.z; BH[kt].i[3] = vh.w;
    }
}

// ---------------------------------------------------------------------------
// Kernel B: EXACT R5/R9 LSTM (measured 260us).  R6 (extra waves -> register
// spill), R7 (in-wave 2x -> linear scaling), and R10 (fusion -> cache-
// maintenance storm) all falsified alternatives; this is the issue floor of
// the structure.
// ---------------------------------------------------------------------------
__global__ __launch_bounds__(512) __attribute__((amdgpu_waves_per_eu(2, 2)))
void lstm_mfma(
    const u16*   __restrict__ x,      // (B*T, 64) bf16 = emb
    const int*   __restrict__ mask,   // (B, T)
    const float* __restrict__ Wih0, const float* __restrict__ Whh0,
    const float* __restrict__ bih0, const float* __restrict__ bhh0,
    const float* __restrict__ Wih1, const float* __restrict__ Whh1,
    const float* __restrict__ bih1, const float* __restrict__ bhh1,
    const float* __restrict__ fc1_w, const float* __restrict__ fc1_b,
    const float* __restrict__ fc2_w, const float* __restrict__ fc2_b,
    float* __restrict__ out)          // (B, 2)
{
    __shared__ __attribute__((aligned(16))) u16 h0s[2][16 * 72];
    __shared__ __attribute__((aligned(16))) u16 h1s[2][16 * 72];
    __shared__ float hlast[16][68];
    __shared__ float red[512];
    __shared__ int   li_s[16];

    const int tid  = threadIdx.x;     // 0..511
    const int w    = tid >> 6;        // wave 0..7
    const int grp  = w >> 2;          // 0: layer 0 (waves 0-3), 1: layer 1
    const int wl   = w & 3;           // wave within layer
    const int lane = tid & 63;
    const int l15  = lane & 15;       // batch col
    const int quad = lane >> 4;
    const int bb0  = blockIdx.x * 16;

    for (int i = tid; i < 16 * 72; i += 512) h1s[0][i] = 0;

    {
        int b16 = tid >> 5, j = tid & 31;
        int s = 0;
        #pragma unroll
        for (int c8 = 0; c8 < 8; ++c8)
            s += mask[(bb0 + b16) * TT + j + 32 * c8];
        red[tid] = (float)s;
    }
    __syncthreads();
    if (tid < 16) {
        float s = 0.f;
        #pragma unroll
        for (int j = 0; j < 32; ++j) s += red[tid * 32 + j];
        int li = (int)s - 1;
        li_s[tid] = li < 0 ? 0 : (li > TT - 1 ? TT - 1 : li);
    }
    __syncthreads();
    const int li = li_s[l15];

    const float* __restrict__ Wx = grp ? Wih1 : Wih0;
    const float* __restrict__ Wh = grp ? Whh1 : Whh0;
    const float* __restrict__ bi = grp ? bih1 : bih0;
    const float* __restrict__ bh = grp ? bhh1 : bhh0;

    Frag Ax[4][2], Ah[4][2];
    f4 biasv[4];
    #pragma unroll
    for (int mt = 0; mt < 4; ++mt) {
        int mg = 4 * wl + mt;
        int orig = (l15 & 3) * 64 + (mg * 4 + (l15 >> 2));
        #pragma unroll
        for (int kt = 0; kt < 2; ++kt)
            #pragma unroll
            for (int p = 0; p < 4; ++p) {
                int k = kt * 32 + quad * 8 + 2 * p;
                Ax[mt][kt].i[p] = pkbf(Wx[orig * 64 + k], Wx[orig * 64 + k + 1]);
                Ah[mt][kt].i[p] = pkbf(Wh[orig * 64 + k], Wh[orig * 64 + k + 1]);
            }
        int uu = mg * 4 + quad;
        #pragma unroll
        for (int r = 0; r < 4; ++r)
            biasv[mt][r] = bi[r * 64 + uu] + bh[r * 64 + uu];
    }
    #pragma unroll
    for (int mt = 0; mt < 4; ++mt) {
        PIN8(Ax[mt][0].s); PIN8(Ax[mt][1].s);
        PIN8(Ah[mt][0].s); PIN8(Ah[mt][1].s);
        PINF(biasv[mt]);
    }

    const int ubase = 16 * wl + quad;
    const int hoff = l15 * 72 + quad * 8;

    Frag BH0[2], BH1[2], BXn[2];
    #pragma unroll
    for (int kt = 0; kt < 2; ++kt)
        #pragma unroll
        for (int p = 0; p < 4; ++p) {
            BXn[kt].i[p] = 0; BH0[kt].i[p] = 0; BH1[kt].i[p] = 0;
        }
    float cst[4] = {0.f, 0.f, 0.f, 0.f};
    float hlv[4] = {0.f, 0.f, 0.f, 0.f};

    const u16* __restrict__ xb = x + (size_t)(bb0 + l15) * TT * 64;
    if (grp == 0) {
        BXn[0] = *(const Frag*)&xb[quad * 8];
        BXn[1] = *(const Frag*)&xb[32 + quad * 8];
    }

    #pragma unroll 1
    for (int it = 0; it <= TT; ++it) {
        const int cur = it & 1;
        f4 g[4];
        bool act = false;

        if (grp == 0) {
            if (it < TT) {
                act = true;
                Frag bx0 = BXn[0], bx1 = BXn[1];
                int tn = it + 1 < TT ? it + 1 : TT - 1;
                BXn[0] = *(const Frag*)&xb[(size_t)tn * 64 + quad * 8];
                BXn[1] = *(const Frag*)&xb[(size_t)tn * 64 + 32 + quad * 8];

                #pragma unroll
                for (int mt = 0; mt < 4; ++mt) {
                    f4 ca = biasv[mt];
                    ca = MFMA(Ax[mt][0].s, bx0.s,    ca);
                    ca = MFMA(Ah[mt][0].s, BH0[0].s, ca);
                    f4 cb = {0.f, 0.f, 0.f, 0.f};
                    cb = MFMA(Ax[mt][1].s, bx1.s,    cb);
                    cb = MFMA(Ah[mt][1].s, BH0[1].s, cb);
                    g[mt] = ca + cb;
                }
            }
        } else {
            if (it >= 1) {
                act = true;
                #pragma unroll
                for (int mt = 0; mt < 4; ++mt) {
                    f4 ca = biasv[mt];
                    ca = MFMA(Ax[mt][0].s, BH0[0].s, ca);
                    ca = MFMA(Ah[mt][0].s, BH1[0].s, ca);
                    f4 cb = {0.f, 0.f, 0.f, 0.f};
                    cb = MFMA(Ax[mt][1].s, BH0[1].s, cb);
                    cb = MFMA(Ah[mt][1].s, BH1[1].s, cb);
                    g[mt] = ca + cb;
                }
            }
        }

        if (act) {
            u16* __restrict__ dst = grp ? h1s[cur] : h0s[cur];
            #pragma unroll
            for (int mt = 0; mt < 4; ++mt) {
                f4 gg = g[mt];
                float si = sigm(gg[0]), sf = sigm(gg[1]);
                float tg = tanha(gg[2]), so = sigm(gg[3]);
                float cc = fmaf(sf, cst[mt], si * tg);
                cst[mt] = cc;
                float h = so * tanha(cc);
                if (grp && it - 1 == li) hlv[mt] = h;
                dst[l15 * 72 + ubase + 4 * mt] = (u16)(unsigned)pkbf(h, h);
            }
        }

        WGBAR();

        if (it < TT) {
            read_h1(h0s[cur], hoff, BH0);
            if (grp) read_h1(h1s[cur], hoff, BH1);
        }
    }

    if (grp == 1) {
        #pragma unroll
        for (int mt = 0; mt < 4; ++mt)
            hlast[l15][ubase + 4 * mt] = hlv[mt];
    }
    __syncthreads();
    {
        int b = tid >> 5, o = tid & 31;
        float acc = fc1_b[o];
        const float* fw = fc1_w + o * 64;
        #pragma unroll
        for (int j = 0; j < 64; ++j)
            acc = fmaf(hlast[b][j], fw[j], acc);
        red[b * 32 + o] = fmaxf(acc, 0.f);
    }
    __syncthreads();
    if (tid < 32) {
        int b = tid >> 1, o = tid & 1;
        float acc = fc2_b[o];
        #pragma unroll
        for (int j = 0; j < 32; ++j)
            acc = fmaf(fc2_w[o * 32 + j], red[b * 32 + j], acc);
        out[(bb0 + b) * 2 + o] = acc;
    }
}

// ---------------------------------------------------------------------------
extern "C" void kernel_launch(void* const* d_in, const int* in_sizes, int n_in,
                              void* d_out, int out_size, void* d_ws, size_t ws_size,
                              hipStream_t stream)
{
    const float* conn  = (const float*)d_in[0];
    const int*   mask  = (const int*)  d_in[1];
    const float* w1_w  = (const float*)d_in[2];
    const float* w1_b  = (const float*)d_in[3];
    const float* w2_w  = (const float*)d_in[4];
    const float* w2_b  = (const float*)d_in[5];
    const float* Wih0  = (const float*)d_in[6];
    const float* Whh0  = (const float*)d_in[7];
    const float* bih0  = (const float*)d_in[8];
    const float* bhh0  = (const float*)d_in[9];
    const float* Wih1  = (const float*)d_in[10];
    const float* Whh1  = (const float*)d_in[11];
    const float* bih1  = (const float*)d_in[12];
    const float* bhh1  = (const float*)d_in[13];
    const float* fc1_w = (const float*)d_in[14];
    const float* fc1_b = (const float*)d_in[15];
    const float* fc2_w = (const float*)d_in[16];
    const float* fc2_b = (const float*)d_in[17];

    float* out = (float*)d_out;
    u16*   emb = (u16*)d_ws;          // 8.4 MB bf16

    const int num_graphs = BB * TT;

    encoder_mfma<<<2048, 256, 0, stream>>>(
        conn, mask, w1_w, w1_b, w2_w, w2_b, emb, num_graphs);

    lstm_mfma<<<16, 512, 0, stream>>>(
        emb, mask, Wih0, Whh0, bih0, bhh0, Wih1, Whh1, bih1, bhh1,
        fc1_w, fc1_b, fc2_w, fc2_b, out);
}